// Round 1
// baseline (196.139 us; speedup 1.0000x reference)
//
#include <hip/hip_runtime.h>
#include <stdint.h>

typedef __attribute__((ext_vector_type(8))) short bf16x8;
typedef __attribute__((ext_vector_type(4))) float f32x4;
typedef __attribute__((ext_vector_type(4))) float float4v;
typedef __attribute__((ext_vector_type(8))) unsigned short u16x8;

#define DEV __device__ __forceinline__

DEV unsigned short f2bf(float f) {
    union { float f; uint32_t u; } v; v.f = f;
    uint32_t u = v.u;
    return (unsigned short)((u + 0x7FFFu + ((u >> 16) & 1u)) >> 16);
}

// ---------------------------------------------------------------------------
// 1) fp32 -> bf16 convert (x), vectorized: 4 f32 in, 4 bf16 (8B) out per thread
// ---------------------------------------------------------------------------
__global__ void k_cvt_x(const float* __restrict__ x, unsigned short* __restrict__ xb, int n4) {
    int i = blockIdx.x * blockDim.x + threadIdx.x;
    if (i >= n4) return;
    float4v v = *(const float4v*)(x + (size_t)i * 4);
    union { unsigned short s[4]; uint64_t q; } o;
    o.s[0] = f2bf(v[0]); o.s[1] = f2bf(v[1]); o.s[2] = f2bf(v[2]); o.s[3] = f2bf(v[3]);
    *(uint64_t*)(xb + (size_t)i * 4) = o.q;
}

// ---------------------------------------------------------------------------
// 2) fp32 [R][C] -> bf16 [C][R] convert + transpose (weights), 64x64 LDS tile
// ---------------------------------------------------------------------------
__global__ void k_cvt_tr_w(const float* __restrict__ w, unsigned short* __restrict__ wt,
                           int R, int C) {
    __shared__ alignas(16) unsigned short tile[64][65];
    const int t = threadIdx.x;
    const int tr = blockIdx.y * 64, tc = blockIdx.x * 64;
#pragma unroll
    for (int p = 0; p < 4; ++p) {
        int r = p * 16 + (t >> 4);
        int c = (t & 15) * 4;
        float4v v = *(const float4v*)(w + (size_t)(tr + r) * C + tc + c);
#pragma unroll
        for (int j = 0; j < 4; ++j) tile[r][c + j] = f2bf(v[j]);
    }
    __syncthreads();
#pragma unroll
    for (int p = 0; p < 2; ++p) {
        int r2 = p * 32 + (t >> 3);   // output row (= col of w)
        int k0 = (t & 7) * 8;         // output col base (= row of w)
        u16x8 o;
#pragma unroll
        for (int j = 0; j < 8; ++j) o[j] = tile[k0 + j][r2];
        *(u16x8*)(wt + (size_t)(tc + r2) * R + tr + k0) = o;
    }
}

// ---------------------------------------------------------------------------
// 3) bf16 GEMM: C[M,N] = A[M,K] * Bt[N,K]^T.  128x128 tile, BK=64, 4 waves,
//    each wave 64x64 (4x4 frags of 16x16x32 MFMA). Register-staged LDS with
//    XOR swizzle on 16B slots -> conflict-free ds_read_b128/ds_write_b128.
//    OUT_BF16=1: store bf16. OUT_BF16=0: store fp32 + bias.
// ---------------------------------------------------------------------------
template <int OUT_BF16>
__global__ __launch_bounds__(256)
void k_gemm_bt(const unsigned short* __restrict__ A,
               const unsigned short* __restrict__ Bt,
               void* __restrict__ Cp, const float* __restrict__ bias,
               int M, int N, int K) {
    __shared__ alignas(16) unsigned short lA[128 * 64];
    __shared__ alignas(16) unsigned short lB[128 * 64];
    const int t = threadIdx.x;
    const int w = t >> 6, l = t & 63;
    const int l15 = l & 15, l4 = l >> 4;
    const int wm = (w >> 1) * 64, wn = (w & 1) * 64;
    const size_t bm = (size_t)blockIdx.y * 128, bn = (size_t)blockIdx.x * 128;

    // LDS read offsets (invariant across K steps)
    int offA[4][2], offB[4][2];
#pragma unroll
    for (int f = 0; f < 4; ++f) {
        const int ra = wm + f * 16 + l15;
        const int rb = wn + f * 16 + l15;
#pragma unroll
        for (int kc = 0; kc < 2; ++kc) {
            offA[f][kc] = ra * 64 + (((kc * 4 + l4) ^ (ra & 7)) << 3);
            offB[f][kc] = rb * 64 + (((kc * 4 + l4) ^ (rb & 7)) << 3);
        }
    }

    const int srow = t >> 3, sslot = t & 7;
    const int swoff = srow * 64 + ((sslot ^ (srow & 7)) << 3);
    const unsigned short* pA = A + (bm + srow) * (size_t)K + sslot * 8;
    const unsigned short* pB = Bt + (bn + srow) * (size_t)K + sslot * 8;

    const f32x4 zf = {0.f, 0.f, 0.f, 0.f};
    f32x4 acc[4][4];
#pragma unroll
    for (int i = 0; i < 4; ++i)
#pragma unroll
        for (int j = 0; j < 4; ++j) acc[i][j] = zf;

    for (int kt = 0; kt < K; kt += 64) {
        bf16x8 ra[4], rb[4];
#pragma unroll
        for (int p = 0; p < 4; ++p) {
            ra[p] = *(const bf16x8*)(pA + (size_t)p * 32 * K + kt);
            rb[p] = *(const bf16x8*)(pB + (size_t)p * 32 * K + kt);
        }
        __syncthreads();   // previous tile fully consumed
#pragma unroll
        for (int p = 0; p < 4; ++p) {
            *(bf16x8*)(lA + p * 32 * 64 + swoff) = ra[p];
            *(bf16x8*)(lB + p * 32 * 64 + swoff) = rb[p];
        }
        __syncthreads();   // tile visible
#pragma unroll
        for (int kc = 0; kc < 2; ++kc) {
            bf16x8 af[4], bfr[4];
#pragma unroll
            for (int f = 0; f < 4; ++f) af[f] = *(const bf16x8*)(lA + offA[f][kc]);
#pragma unroll
            for (int f = 0; f < 4; ++f) bfr[f] = *(const bf16x8*)(lB + offB[f][kc]);
#pragma unroll
            for (int mf = 0; mf < 4; ++mf)
#pragma unroll
                for (int nf = 0; nf < 4; ++nf)
                    acc[mf][nf] = __builtin_amdgcn_mfma_f32_16x16x32_bf16(
                        af[mf], bfr[nf], acc[mf][nf], 0, 0, 0);
        }
    }

    if (OUT_BF16) {
        unsigned short* C = (unsigned short*)Cp;
#pragma unroll
        for (int mf = 0; mf < 4; ++mf)
#pragma unroll
            for (int nf = 0; nf < 4; ++nf) {
                const size_t row = bm + wm + mf * 16 + l4 * 4;
                const size_t col = bn + wn + nf * 16 + l15;
#pragma unroll
                for (int j = 0; j < 4; ++j)
                    C[(row + j) * (size_t)N + col] = f2bf(acc[mf][nf][j]);
            }
    } else {
        float* C = (float*)Cp;
#pragma unroll
        for (int nf = 0; nf < 4; ++nf) {
            const size_t col = bn + wn + nf * 16 + l15;
            const float bv = bias[col];
#pragma unroll
            for (int mf = 0; mf < 4; ++mf) {
                const size_t row = bm + wm + mf * 16 + l4 * 4;
#pragma unroll
                for (int j = 0; j < 4; ++j)
                    C[(row + j) * (size_t)N + col] = acc[mf][nf][j] + bv;
            }
        }
    }
}

// ---------------------------------------------------------------------------
// 4) V transpose: qkv v-cols [b,n,h*64+d] -> vt[bh][d][n]  (so PV B-operand
//    is a contiguous 16B row read from LDS)
// ---------------------------------------------------------------------------
__global__ void k_tr_v(const unsigned short* __restrict__ qkv, unsigned short* __restrict__ vt) {
    __shared__ alignas(16) unsigned short tile[64][72];
    const int t = threadIdx.x;
    const int bh = blockIdx.y, b = bh >> 4, h = bh & 15;
    const int nb = blockIdx.x * 64;
#pragma unroll
    for (int p = 0; p < 2; ++p) {
        const int n = p * 32 + (t >> 3), d0 = (t & 7) * 8;
        u16x8 v = *(const u16x8*)(qkv + (size_t)(b * 2048 + nb + n) * 3072 + 2048 + h * 64 + d0);
#pragma unroll
        for (int j = 0; j < 8; ++j) tile[d0 + j][n] = v[j];
    }
    __syncthreads();
#pragma unroll
    for (int p = 0; p < 2; ++p) {
        const int d = p * 32 + (t >> 3), n0 = (t & 7) * 8;
        u16x8 v = *(const u16x8*)(&tile[d][n0]);
        *(u16x8*)(vt + (size_t)(bh * 64 + d) * 2048 + nb + n0) = v;
    }
}

// ---------------------------------------------------------------------------
// 5) Flash attention: grid (qtile, bh). 4 waves x 16 q-rows = 64 q-rows/block.
//    KV tiles of 64. Online softmax fp32. K & Vt staged in XOR-swizzled LDS.
//    P goes through per-wave swizzled LDS (C-frag layout -> A-frag layout).
// ---------------------------------------------------------------------------
__global__ __launch_bounds__(256)
void k_attn(const unsigned short* __restrict__ qkv, const unsigned short* __restrict__ vt,
            unsigned short* __restrict__ attn_out) {
    __shared__ alignas(16) unsigned short lK[64 * 64];
    __shared__ alignas(16) unsigned short lV[64 * 64];
    __shared__ alignas(16) unsigned short lP[4][16 * 64];
    const int t = threadIdx.x, w = t >> 6, l = t & 63;
    const int l15 = l & 15, l4 = l >> 4;
    const int bh = blockIdx.y, b = bh >> 4, h = bh & 15;
    const int qb = blockIdx.x * 64;
    const float LOG2E = 1.4426950408889634f;
    const float SCALE = 0.125f;   // 1/sqrt(64)

    // Q fragments held in registers for the whole KV loop
    const unsigned short* qptr =
        qkv + (size_t)(b * 2048 + qb + w * 16 + l15) * 3072 + h * 64 + l4 * 8;
    const bf16x8 aq0 = *(const bf16x8*)(qptr);
    const bf16x8 aq1 = *(const bf16x8*)(qptr + 32);

    const int srow = t >> 3, sslot = t & 7;
    const int swoff = srow * 64 + ((sslot ^ (srow & 7)) << 3);
    const unsigned short* kptr = qkv + (size_t)(b * 2048 + srow) * 3072 + 1024 + h * 64 + sslot * 8;
    const unsigned short* vptr = vt + (size_t)(bh * 64 + srow) * 2048 + sslot * 8;

    const f32x4 zf = {0.f, 0.f, 0.f, 0.f};
    f32x4 o[4];
#pragma unroll
    for (int nf = 0; nf < 4; ++nf) o[nf] = zf;
    float m_run[4] = {-1e30f, -1e30f, -1e30f, -1e30f};
    float l_run[4] = {0.f, 0.f, 0.f, 0.f};
    unsigned short* Pw = &lP[w][0];

    for (int kt = 0; kt < 2048; kt += 64) {
        bf16x8 rk[2], rv[2];
#pragma unroll
        for (int p = 0; p < 2; ++p) {
            rk[p] = *(const bf16x8*)(kptr + (size_t)(kt + p * 32) * 3072);
            rv[p] = *(const bf16x8*)(vptr + (size_t)(p * 32) * 2048 + kt);
        }
        __syncthreads();
#pragma unroll
        for (int p = 0; p < 2; ++p) {
            *(bf16x8*)(lK + p * 32 * 64 + swoff) = rk[p];
            *(bf16x8*)(lV + p * 32 * 64 + swoff) = rv[p];
        }
        __syncthreads();

        // S = Q K^T   (rows: 16 q, cols: 64 kv)
        f32x4 s[4];
#pragma unroll
        for (int nf = 0; nf < 4; ++nf) {
            const int r = nf * 16 + l15;
            const bf16x8 bk0 = *(const bf16x8*)(lK + r * 64 + ((l4 ^ (r & 7)) << 3));
            const bf16x8 bk1 = *(const bf16x8*)(lK + r * 64 + (((4 + l4) ^ (r & 7)) << 3));
            f32x4 a = zf;
            a = __builtin_amdgcn_mfma_f32_16x16x32_bf16(aq0, bk0, a, 0, 0, 0);
            a = __builtin_amdgcn_mfma_f32_16x16x32_bf16(aq1, bk1, a, 0, 0, 0);
            s[nf] = a;
        }
        // scale + row max (across 64 cols: 4 frags in-reg, then 16-lane shfl)
        float mx[4];
#pragma unroll
        for (int j = 0; j < 4; ++j) {
#pragma unroll
            for (int nf = 0; nf < 4; ++nf) s[nf][j] *= SCALE;
            mx[j] = fmaxf(fmaxf(s[0][j], s[1][j]), fmaxf(s[2][j], s[3][j]));
        }
#pragma unroll
        for (int off = 1; off < 16; off <<= 1)
#pragma unroll
            for (int j = 0; j < 4; ++j) mx[j] = fmaxf(mx[j], __shfl_xor(mx[j], off));

        float alpha[4], rs[4];
#pragma unroll
        for (int j = 0; j < 4; ++j) {
            const float mn = fmaxf(m_run[j], mx[j]);
            alpha[j] = exp2f((m_run[j] - mn) * LOG2E);
            m_run[j] = mn;
            rs[j] = 0.f;
        }
        // P = exp(S - m), write bf16 into per-wave swizzled LDS (C->A relayout)
#pragma unroll
        for (int nf = 0; nf < 4; ++nf) {
#pragma unroll
            for (int j = 0; j < 4; ++j) {
                const float p = exp2f((s[nf][j] - m_run[j]) * LOG2E);
                rs[j] += p;
                const int row = l4 * 4 + j;
                const int col = nf * 16 + l15;
                Pw[row * 64 + (((col >> 3) ^ (row & 7)) << 3) + (col & 7)] = f2bf(p);
            }
        }
#pragma unroll
        for (int off = 1; off < 16; off <<= 1)
#pragma unroll
            for (int j = 0; j < 4; ++j) rs[j] += __shfl_xor(rs[j], off);
#pragma unroll
        for (int j = 0; j < 4; ++j) l_run[j] = l_run[j] * alpha[j] + rs[j];
#pragma unroll
        for (int nf = 0; nf < 4; ++nf)
#pragma unroll
            for (int j = 0; j < 4; ++j) o[nf][j] *= alpha[j];

        // O += P V   (A-frags of P from LDS; B-frags from Vt rows = d)
        const bf16x8 ap0 = *(const bf16x8*)(Pw + l15 * 64 + ((l4 ^ (l15 & 7)) << 3));
        const bf16x8 ap1 = *(const bf16x8*)(Pw + l15 * 64 + (((4 + l4) ^ (l15 & 7)) << 3));
#pragma unroll
        for (int nf = 0; nf < 4; ++nf) {
            const int r = nf * 16 + l15;
            const bf16x8 bv0 = *(const bf16x8*)(lV + r * 64 + ((l4 ^ (r & 7)) << 3));
            const bf16x8 bv1 = *(const bf16x8*)(lV + r * 64 + (((4 + l4) ^ (r & 7)) << 3));
            o[nf] = __builtin_amdgcn_mfma_f32_16x16x32_bf16(ap0, bv0, o[nf], 0, 0, 0);
            o[nf] = __builtin_amdgcn_mfma_f32_16x16x32_bf16(ap1, bv1, o[nf], 0, 0, 0);
        }
    }

    // epilogue: O / l  -> attn_out[b, n, h*64+d] bf16
#pragma unroll
    for (int nf = 0; nf < 4; ++nf) {
        const int d = nf * 16 + l15;
#pragma unroll
        for (int j = 0; j < 4; ++j) {
            const float v = o[nf][j] / l_run[j];
            const size_t row = (size_t)(b * 2048 + qb + w * 16 + l4 * 4 + j);
            attn_out[row * 1024 + h * 64 + d] = f2bf(v);
        }
    }
}

// ---------------------------------------------------------------------------
extern "C" void kernel_launch(void* const* d_in, const int* in_sizes, int n_in,
                              void* d_out, int out_size, void* d_ws, size_t ws_size,
                              hipStream_t stream) {
    const float* x      = (const float*)d_in[0];
    const float* w_qkv  = (const float*)d_in[1];
    const float* w_proj = (const float*)d_in[2];
    const float* b_proj = (const float*)d_in[3];
    float* out = (float*)d_out;

    char* ws = (char*)d_ws;
    unsigned short* xb     = (unsigned short*)ws; ws += (size_t)4096 * 1024 * 2;
    unsigned short* wqkvT  = (unsigned short*)ws; ws += (size_t)3072 * 1024 * 2;
    unsigned short* wprojT = (unsigned short*)ws; ws += (size_t)1024 * 1024 * 2;
    unsigned short* qkv    = (unsigned short*)ws; ws += (size_t)4096 * 3072 * 2;
    unsigned short* vt     = (unsigned short*)ws; ws += (size_t)32 * 64 * 2048 * 2;
    unsigned short* attn   = (unsigned short*)ws; ws += (size_t)4096 * 1024 * 2;

    k_cvt_x<<<dim3(4096), dim3(256), 0, stream>>>(x, xb, 4096 * 1024 / 4);
    k_cvt_tr_w<<<dim3(48, 16), dim3(256), 0, stream>>>(w_qkv, wqkvT, 1024, 3072);
    k_cvt_tr_w<<<dim3(16, 16), dim3(256), 0, stream>>>(w_proj, wprojT, 1024, 1024);
    k_gemm_bt<1><<<dim3(24, 32), dim3(256), 0, stream>>>(xb, wqkvT, (void*)qkv, (const float*)nullptr, 4096, 3072, 1024);
    k_tr_v<<<dim3(32, 32), dim3(256), 0, stream>>>(qkv, vt);
    k_attn<<<dim3(32, 32), dim3(256), 0, stream>>>(qkv, vt, attn);
    k_gemm_bt<0><<<dim3(8, 32), dim3(256), 0, stream>>>(attn, wprojT, (void*)out, b_proj, 4096, 1024, 1024);
}

// Round 4
// 161.699 us; speedup vs baseline: 1.2130x; 1.2130x over previous
//
#include <hip/hip_runtime.h>
#include <stdint.h>

typedef __attribute__((ext_vector_type(8))) short bf16x8;
typedef __attribute__((ext_vector_type(4))) float f32x4;
typedef __attribute__((ext_vector_type(4))) float float4v;
typedef __attribute__((ext_vector_type(8))) unsigned short u16x8;

#define DEV __device__ __forceinline__

DEV unsigned short f2bf(float f) {
    union { float f; uint32_t u; } v; v.f = f;
    uint32_t u = v.u;
    return (unsigned short)((u + 0x7FFFu + ((u >> 16) & 1u)) >> 16);
}

DEV unsigned int cvt_pk_bf16(float lo, float hi) {
    unsigned int r;
    asm("v_cvt_pk_bf16_f32 %0, %1, %2" : "=v"(r) : "v"(lo), "v"(hi));
    return r;
}

// ---------------------------------------------------------------------------
// 1) fp32 -> bf16 convert (x)
// ---------------------------------------------------------------------------
__global__ void k_cvt_x(const float* __restrict__ x, unsigned short* __restrict__ xb, int n4) {
    int i = blockIdx.x * blockDim.x + threadIdx.x;
    if (i >= n4) return;
    float4v v = *(const float4v*)(x + (size_t)i * 4);
    union { unsigned short s[4]; uint64_t q; } o;
    o.s[0] = f2bf(v[0]); o.s[1] = f2bf(v[1]); o.s[2] = f2bf(v[2]); o.s[3] = f2bf(v[3]);
    *(uint64_t*)(xb + (size_t)i * 4) = o.q;
}

// ---------------------------------------------------------------------------
// 2) fp32 [R][C] -> bf16 [C][R] convert + transpose
// ---------------------------------------------------------------------------
__global__ void k_cvt_tr_w(const float* __restrict__ w, unsigned short* __restrict__ wt,
                           int R, int C) {
    __shared__ alignas(16) unsigned short tile[64][65];
    const int t = threadIdx.x;
    const int tr = blockIdx.y * 64, tc = blockIdx.x * 64;
#pragma unroll
    for (int p = 0; p < 4; ++p) {
        int r = p * 16 + (t >> 4);
        int c = (t & 15) * 4;
        float4v v = *(const float4v*)(w + (size_t)(tr + r) * C + tc + c);
#pragma unroll
        for (int j = 0; j < 4; ++j) tile[r][c + j] = f2bf(v[j]);
    }
    __syncthreads();
#pragma unroll
    for (int p = 0; p < 2; ++p) {
        int r2 = p * 32 + (t >> 3);
        int k0 = (t & 7) * 8;
        u16x8 o;
#pragma unroll
        for (int j = 0; j < 8; ++j) o[j] = tile[k0 + j][r2];
        *(u16x8*)(wt + (size_t)(tc + r2) * R + tr + k0) = o;
    }
}

// ---------------------------------------------------------------------------
// 3) bf16 GEMM: C[M,N] = A[M,K] * Bt[N,K]^T.  128x128 tile, BK=64, 4 waves.
// ---------------------------------------------------------------------------
template <int OUT_BF16>
__global__ __launch_bounds__(256)
void k_gemm_bt(const unsigned short* __restrict__ A,
               const unsigned short* __restrict__ Bt,
               void* __restrict__ Cp, const float* __restrict__ bias,
               int M, int N, int K) {
    __shared__ alignas(16) unsigned short lA[128 * 64];
    __shared__ alignas(16) unsigned short lB[128 * 64];
    const int t = threadIdx.x;
    const int w = t >> 6, l = t & 63;
    const int l15 = l & 15, l4 = l >> 4;
    const int wm = (w >> 1) * 64, wn = (w & 1) * 64;
    const size_t bm = (size_t)blockIdx.y * 128, bn = (size_t)blockIdx.x * 128;

    int offA[4][2], offB[4][2];
#pragma unroll
    for (int f = 0; f < 4; ++f) {
        const int ra = wm + f * 16 + l15;
        const int rb = wn + f * 16 + l15;
#pragma unroll
        for (int kc = 0; kc < 2; ++kc) {
            offA[f][kc] = ra * 64 + (((kc * 4 + l4) ^ (ra & 7)) << 3);
            offB[f][kc] = rb * 64 + (((kc * 4 + l4) ^ (rb & 7)) << 3);
        }
    }

    const int srow = t >> 3, sslot = t & 7;
    const int swoff = srow * 64 + ((sslot ^ (srow & 7)) << 3);
    const unsigned short* pA = A + (bm + srow) * (size_t)K + sslot * 8;
    const unsigned short* pB = Bt + (bn + srow) * (size_t)K + sslot * 8;

    const f32x4 zf = {0.f, 0.f, 0.f, 0.f};
    f32x4 acc[4][4];
#pragma unroll
    for (int i = 0; i < 4; ++i)
#pragma unroll
        for (int j = 0; j < 4; ++j) acc[i][j] = zf;

    for (int kt = 0; kt < K; kt += 64) {
        bf16x8 ra[4], rb[4];
#pragma unroll
        for (int p = 0; p < 4; ++p) {
            ra[p] = *(const bf16x8*)(pA + (size_t)p * 32 * K + kt);
            rb[p] = *(const bf16x8*)(pB + (size_t)p * 32 * K + kt);
        }
        __syncthreads();
#pragma unroll
        for (int p = 0; p < 4; ++p) {
            *(bf16x8*)(lA + p * 32 * 64 + swoff) = ra[p];
            *(bf16x8*)(lB + p * 32 * 64 + swoff) = rb[p];
        }
        __syncthreads();
#pragma unroll
        for (int kc = 0; kc < 2; ++kc) {
            bf16x8 af[4], bfr[4];
#pragma unroll
            for (int f = 0; f < 4; ++f) af[f] = *(const bf16x8*)(lA + offA[f][kc]);
#pragma unroll
            for (int f = 0; f < 4; ++f) bfr[f] = *(const bf16x8*)(lB + offB[f][kc]);
#pragma unroll
            for (int mf = 0; mf < 4; ++mf)
#pragma unroll
                for (int nf = 0; nf < 4; ++nf)
                    acc[mf][nf] = __builtin_amdgcn_mfma_f32_16x16x32_bf16(
                        af[mf], bfr[nf], acc[mf][nf], 0, 0, 0);
        }
    }

    if (OUT_BF16) {
        unsigned short* C = (unsigned short*)Cp;
#pragma unroll
        for (int mf = 0; mf < 4; ++mf)
#pragma unroll
            for (int nf = 0; nf < 4; ++nf) {
                const size_t row = bm + wm + mf * 16 + l4 * 4;
                const size_t col = bn + wn + nf * 16 + l15;
#pragma unroll
                for (int j = 0; j < 4; ++j)
                    C[(row + j) * (size_t)N + col] = f2bf(acc[mf][nf][j]);
            }
    } else {
        float* C = (float*)Cp;
#pragma unroll
        for (int nf = 0; nf < 4; ++nf) {
            const size_t col = bn + wn + nf * 16 + l15;
            const float bv = bias[col];
#pragma unroll
            for (int mf = 0; mf < 4; ++mf) {
                const size_t row = bm + wm + mf * 16 + l4 * 4;
#pragma unroll
                for (int j = 0; j < 4; ++j)
                    C[(row + j) * (size_t)N + col] = acc[mf][nf][j] + bv;
            }
        }
    }
}

// ---------------------------------------------------------------------------
// 4) V transpose: qkv v-cols -> vt[bh][d][n]
// ---------------------------------------------------------------------------
__global__ void k_tr_v(const unsigned short* __restrict__ qkv, unsigned short* __restrict__ vt) {
    __shared__ alignas(16) unsigned short tile[64][72];
    const int t = threadIdx.x;
    const int bh = blockIdx.y, b = bh >> 4, h = bh & 15;
    const int nb = blockIdx.x * 64;
#pragma unroll
    for (int p = 0; p < 2; ++p) {
        const int n = p * 32 + (t >> 3), d0 = (t & 7) * 8;
        u16x8 v = *(const u16x8*)(qkv + (size_t)(b * 2048 + nb + n) * 3072 + 2048 + h * 64 + d0);
#pragma unroll
        for (int j = 0; j < 8; ++j) tile[d0 + j][n] = v[j];
    }
    __syncthreads();
#pragma unroll
    for (int p = 0; p < 2; ++p) {
        const int d = p * 32 + (t >> 3), n0 = (t & 7) * 8;
        u16x8 v = *(const u16x8*)(&tile[d][n0]);
        *(u16x8*)(vt + (size_t)(bh * 64 + d) * 2048 + nb + n0) = v;
    }
}

// ---------------------------------------------------------------------------
// 5) Flash attention, swapped-QK, ALL-VERIFIED opcodes (16x16x32 MFMA only).
//    Per tile: S^T = mfma(K,Q) -> lane owns 16 S values for q=l15 -> in-reg
//    max tree + 2 shfl -> per-tile rescale (alpha broadcast via 4 shfl) ->
//    P packed (cvt_pk) into per-wave LDS [q=16][kv=64] (round-1 swizzle) ->
//    PV via round-1-identical x32 A-frag reads. Rowsum in-lane + 2 shfl.
//    Single-buffer K/V staging, 2 barriers/iter (round-1-identical).
// ---------------------------------------------------------------------------
__global__ __launch_bounds__(256)
void k_attn(const unsigned short* __restrict__ qkv, const unsigned short* __restrict__ vt,
            unsigned short* __restrict__ attn_out) {
    __shared__ alignas(16) unsigned short lK[64 * 64];
    __shared__ alignas(16) unsigned short lV[64 * 64];
    __shared__ alignas(16) unsigned short lP[4][16 * 64];
    const int t = threadIdx.x, w = t >> 6, l = t & 63;
    const int l15 = l & 15, l4 = l >> 4;
    const int bh = blockIdx.y, b = bh >> 4, h = bh & 15;
    const int qb = blockIdx.x * 64;
    const float QSCALE = 0.18033688011112042f;   // 0.125 * log2(e)

    // Q B-frags in registers for the whole KV loop
    const unsigned short* qptr =
        qkv + (size_t)(b * 2048 + qb + w * 16 + l15) * 3072 + h * 64 + l4 * 8;
    const bf16x8 aq0 = *(const bf16x8*)(qptr);
    const bf16x8 aq1 = *(const bf16x8*)(qptr + 32);

    const int srow = t >> 3, sslot = t & 7;
    const int swoff = srow * 64 + ((sslot ^ (srow & 7)) << 3);
    const unsigned short* kptr = qkv + (size_t)(b * 2048 + srow) * 3072 + 1024 + h * 64 + sslot * 8;
    const unsigned short* vptr = vt + (size_t)(bh * 64 + srow) * 2048 + sslot * 8;

    // K A-frag offsets (swapped QK: A = K rows kv = nf*16+l15)
    int offK[4][2];
#pragma unroll
    for (int nf = 0; nf < 4; ++nf) {
        const int r = nf * 16 + l15;
#pragma unroll
        for (int kc = 0; kc < 2; ++kc)
            offK[nf][kc] = r * 64 + (((kc * 4 + l4) ^ (r & 7)) << 3);
    }
    // P LDS write offsets: value pair (q=l15, kv = nf*16 + l4*4 + h2*2)
    int offPw[4][2];
#pragma unroll
    for (int nf = 0; nf < 4; ++nf) {
#pragma unroll
        for (int h2 = 0; h2 < 2; ++h2) {
            const int c = nf * 16 + l4 * 4 + h2 * 2;
            offPw[nf][h2] = l15 * 64 + (((c >> 3) ^ (l15 & 7)) << 3) + (c & 7);
        }
    }

    const f32x4 zf = {0.f, 0.f, 0.f, 0.f};
    f32x4 o[4];
#pragma unroll
    for (int df = 0; df < 4; ++df) o[df] = zf;
    float m_run = -1e30f;
    float l_run = 0.f;
    unsigned short* Pw = &lP[w][0];

    for (int kt = 0; kt < 2048; kt += 64) {
        bf16x8 rk[2], rv[2];
#pragma unroll
        for (int p = 0; p < 2; ++p) {
            rk[p] = *(const bf16x8*)(kptr + (size_t)(kt + p * 32) * 3072);
            rv[p] = *(const bf16x8*)(vptr + (size_t)(p * 32) * 2048 + kt);
        }
        __syncthreads();
#pragma unroll
        for (int p = 0; p < 2; ++p) {
            *(bf16x8*)(lK + p * 32 * 64 + swoff) = rk[p];
            *(bf16x8*)(lV + p * 32 * 64 + swoff) = rv[p];
        }
        __syncthreads();

        // S^T = K Q^T : lane holds S_raw[kv = nf*16 + l4*4 + j][q = l15]
        f32x4 s[4];
#pragma unroll
        for (int nf = 0; nf < 4; ++nf) {
            const bf16x8 kf0 = *(const bf16x8*)(lK + offK[nf][0]);
            const bf16x8 kf1 = *(const bf16x8*)(lK + offK[nf][1]);
            f32x4 a = zf;
            a = __builtin_amdgcn_mfma_f32_16x16x32_bf16(kf0, aq0, a, 0, 0, 0);
            a = __builtin_amdgcn_mfma_f32_16x16x32_bf16(kf1, aq1, a, 0, 0, 0);
            s[nf] = a;
        }

        // max over raw s (QSCALE > 0 commutes with max): 15-op tree + 2 shfl
        float mx = fmaxf(fmaxf(fmaxf(s[0][0], s[0][1]), fmaxf(s[0][2], s[0][3])),
                         fmaxf(fmaxf(s[1][0], s[1][1]), fmaxf(s[1][2], s[1][3])));
        mx = fmaxf(mx, fmaxf(fmaxf(fmaxf(s[2][0], s[2][1]), fmaxf(s[2][2], s[2][3])),
                             fmaxf(fmaxf(s[3][0], s[3][1]), fmaxf(s[3][2], s[3][3]))));
        mx = fmaxf(mx, __shfl_xor(mx, 16));
        mx = fmaxf(mx, __shfl_xor(mx, 32));
        mx *= QSCALE;   // into scaled log2 domain

        // per-tile rescale
        const float mn = fmaxf(m_run, mx);
        const float alpha = exp2f(m_run - mn);
        m_run = mn;
        {
            const float a0 = __shfl(alpha, l4 * 4 + 0);
            const float a1 = __shfl(alpha, l4 * 4 + 1);
            const float a2 = __shfl(alpha, l4 * 4 + 2);
            const float a3 = __shfl(alpha, l4 * 4 + 3);
#pragma unroll
            for (int df = 0; df < 4; ++df) {
                o[df][0] *= a0; o[df][1] *= a1; o[df][2] *= a2; o[df][3] *= a3;
            }
        }

        // P = exp2(QSCALE*s_raw - m); rowsum in fp32; pack to LDS (b32 writes)
        float rs = 0.f;
#pragma unroll
        for (int nf = 0; nf < 4; ++nf) {
            const float p0 = exp2f(fmaf(s[nf][0], QSCALE, -m_run));
            const float p1 = exp2f(fmaf(s[nf][1], QSCALE, -m_run));
            const float p2 = exp2f(fmaf(s[nf][2], QSCALE, -m_run));
            const float p3 = exp2f(fmaf(s[nf][3], QSCALE, -m_run));
            rs += (p0 + p1) + (p2 + p3);
            *(unsigned int*)(Pw + offPw[nf][0]) = cvt_pk_bf16(p0, p1);
            *(unsigned int*)(Pw + offPw[nf][1]) = cvt_pk_bf16(p2, p3);
        }
        rs += __shfl_xor(rs, 16);
        rs += __shfl_xor(rs, 32);
        l_run = l_run * alpha + rs;

        // O += P V  (round-1-identical A-frag reads + x32 MFMA)
        const bf16x8 ap0 = *(const bf16x8*)(Pw + l15 * 64 + ((l4 ^ (l15 & 7)) << 3));
        const bf16x8 ap1 = *(const bf16x8*)(Pw + l15 * 64 + (((4 + l4) ^ (l15 & 7)) << 3));
#pragma unroll
        for (int df = 0; df < 4; ++df) {
            const int r = df * 16 + l15;
            const bf16x8 bv0 = *(const bf16x8*)(lV + r * 64 + ((l4 ^ (r & 7)) << 3));
            const bf16x8 bv1 = *(const bf16x8*)(lV + r * 64 + (((4 + l4) ^ (r & 7)) << 3));
            o[df] = __builtin_amdgcn_mfma_f32_16x16x32_bf16(ap0, bv0, o[df], 0, 0, 0);
            o[df] = __builtin_amdgcn_mfma_f32_16x16x32_bf16(ap1, bv1, o[df], 0, 0, 0);
        }
    }

    // epilogue: O / l  (broadcast 1/l from softmax lanes to o's q rows)
    const float linv = 1.0f / l_run;
    const float r0 = __shfl(linv, l4 * 4 + 0);
    const float r1 = __shfl(linv, l4 * 4 + 1);
    const float r2 = __shfl(linv, l4 * 4 + 2);
    const float r3 = __shfl(linv, l4 * 4 + 3);
#pragma unroll
    for (int df = 0; df < 4; ++df) {
        const int d = df * 16 + l15;
        const size_t base = (size_t)(b * 2048 + qb + w * 16 + l4 * 4);
        attn_out[(base + 0) * 1024 + h * 64 + d] = f2bf(o[df][0] * r0);
        attn_out[(base + 1) * 1024 + h * 64 + d] = f2bf(o[df][1] * r1);
        attn_out[(base + 2) * 1024 + h * 64 + d] = f2bf(o[df][2] * r2);
        attn_out[(base + 3) * 1024 + h * 64 + d] = f2bf(o[df][3] * r3);
    }
}

// ---------------------------------------------------------------------------
extern "C" void kernel_launch(void* const* d_in, const int* in_sizes, int n_in,
                              void* d_out, int out_size, void* d_ws, size_t ws_size,
                              hipStream_t stream) {
    const float* x      = (const float*)d_in[0];
    const float* w_qkv  = (const float*)d_in[1];
    const float* w_proj = (const float*)d_in[2];
    const float* b_proj = (const float*)d_in[3];
    float* out = (float*)d_out;

    char* ws = (char*)d_ws;
    unsigned short* xb     = (unsigned short*)ws; ws += (size_t)4096 * 1024 * 2;
    unsigned short* wqkvT  = (unsigned short*)ws; ws += (size_t)3072 * 1024 * 2;
    unsigned short* wprojT = (unsigned short*)ws; ws += (size_t)1024 * 1024 * 2;
    unsigned short* qkv    = (unsigned short*)ws; ws += (size_t)4096 * 3072 * 2;
    unsigned short* vt     = (unsigned short*)ws; ws += (size_t)32 * 64 * 2048 * 2;
    unsigned short* attn   = (unsigned short*)ws; ws += (size_t)4096 * 1024 * 2;

    k_cvt_x<<<dim3(4096), dim3(256), 0, stream>>>(x, xb, 4096 * 1024 / 4);
    k_cvt_tr_w<<<dim3(48, 16), dim3(256), 0, stream>>>(w_qkv, wqkvT, 1024, 3072);
    k_cvt_tr_w<<<dim3(16, 16), dim3(256), 0, stream>>>(w_proj, wprojT, 1024, 1024);
    k_gemm_bt<1><<<dim3(24, 32), dim3(256), 0, stream>>>(xb, wqkvT, (void*)qkv, (const float*)nullptr, 4096, 3072, 1024);
    k_tr_v<<<dim3(32, 32), dim3(256), 0, stream>>>(qkv, vt);
    k_attn<<<dim3(32, 32), dim3(256), 0, stream>>>(qkv, vt, attn);
    k_gemm_bt<0><<<dim3(8, 32), dim3(256), 0, stream>>>(attn, wprojT, (void*)out, b_proj, 4096, 1024, 1024);
}

// Round 5
// 149.062 us; speedup vs baseline: 1.3158x; 1.0848x over previous
//
#include <hip/hip_runtime.h>
#include <stdint.h>

typedef __attribute__((ext_vector_type(8))) short bf16x8;
typedef __attribute__((ext_vector_type(4))) float f32x4;
typedef __attribute__((ext_vector_type(4))) float float4v;
typedef __attribute__((ext_vector_type(8))) unsigned short u16x8;

#define DEV __device__ __forceinline__

DEV unsigned short f2bf(float f) {
    union { float f; uint32_t u; } v; v.f = f;
    uint32_t u = v.u;
    return (unsigned short)((u + 0x7FFFu + ((u >> 16) & 1u)) >> 16);
}

DEV unsigned int cvt_pk_bf16(float lo, float hi) {
    unsigned int r;
    asm("v_cvt_pk_bf16_f32 %0, %1, %2" : "=v"(r) : "v"(lo), "v"(hi));
    return r;
}

// ---------------------------------------------------------------------------
// 1) fp32 -> bf16 convert (x)
// ---------------------------------------------------------------------------
__global__ void k_cvt_x(const float* __restrict__ x, unsigned short* __restrict__ xb, int n4) {
    int i = blockIdx.x * blockDim.x + threadIdx.x;
    if (i >= n4) return;
    float4v v = *(const float4v*)(x + (size_t)i * 4);
    union { unsigned short s[4]; uint64_t q; } o;
    o.s[0] = f2bf(v[0]); o.s[1] = f2bf(v[1]); o.s[2] = f2bf(v[2]); o.s[3] = f2bf(v[3]);
    *(uint64_t*)(xb + (size_t)i * 4) = o.q;
}

// ---------------------------------------------------------------------------
// 2) fp32 [R][C] -> bf16 [C][R] convert + transpose
// ---------------------------------------------------------------------------
__global__ void k_cvt_tr_w(const float* __restrict__ w, unsigned short* __restrict__ wt,
                           int R, int C) {
    __shared__ alignas(16) unsigned short tile[64][65];
    const int t = threadIdx.x;
    const int tr = blockIdx.y * 64, tc = blockIdx.x * 64;
#pragma unroll
    for (int p = 0; p < 4; ++p) {
        int r = p * 16 + (t >> 4);
        int c = (t & 15) * 4;
        float4v v = *(const float4v*)(w + (size_t)(tr + r) * C + tc + c);
#pragma unroll
        for (int j = 0; j < 4; ++j) tile[r][c + j] = f2bf(v[j]);
    }
    __syncthreads();
#pragma unroll
    for (int p = 0; p < 2; ++p) {
        int r2 = p * 32 + (t >> 3);
        int k0 = (t & 7) * 8;
        u16x8 o;
#pragma unroll
        for (int j = 0; j < 8; ++j) o[j] = tile[k0 + j][r2];
        *(u16x8*)(wt + (size_t)(tc + r2) * R + tr + k0) = o;
    }
}

// ---------------------------------------------------------------------------
// 3) bf16 GEMM: C[M,N] = A[M,K] * Bt[N,K]^T.  128x128 tile, BK=64, 4 waves.
// ---------------------------------------------------------------------------
template <int OUT_BF16>
__global__ __launch_bounds__(256)
void k_gemm_bt(const unsigned short* __restrict__ A,
               const unsigned short* __restrict__ Bt,
               void* __restrict__ Cp, const float* __restrict__ bias,
               int M, int N, int K) {
    __shared__ alignas(16) unsigned short lA[128 * 64];
    __shared__ alignas(16) unsigned short lB[128 * 64];
    const int t = threadIdx.x;
    const int w = t >> 6, l = t & 63;
    const int l15 = l & 15, l4 = l >> 4;
    const int wm = (w >> 1) * 64, wn = (w & 1) * 64;
    const size_t bm = (size_t)blockIdx.y * 128, bn = (size_t)blockIdx.x * 128;

    int offA[4][2], offB[4][2];
#pragma unroll
    for (int f = 0; f < 4; ++f) {
        const int ra = wm + f * 16 + l15;
        const int rb = wn + f * 16 + l15;
#pragma unroll
        for (int kc = 0; kc < 2; ++kc) {
            offA[f][kc] = ra * 64 + (((kc * 4 + l4) ^ (ra & 7)) << 3);
            offB[f][kc] = rb * 64 + (((kc * 4 + l4) ^ (rb & 7)) << 3);
        }
    }

    const int srow = t >> 3, sslot = t & 7;
    const int swoff = srow * 64 + ((sslot ^ (srow & 7)) << 3);
    const unsigned short* pA = A + (bm + srow) * (size_t)K + sslot * 8;
    const unsigned short* pB = Bt + (bn + srow) * (size_t)K + sslot * 8;

    const f32x4 zf = {0.f, 0.f, 0.f, 0.f};
    f32x4 acc[4][4];
#pragma unroll
    for (int i = 0; i < 4; ++i)
#pragma unroll
        for (int j = 0; j < 4; ++j) acc[i][j] = zf;

    for (int kt = 0; kt < K; kt += 64) {
        bf16x8 ra[4], rb[4];
#pragma unroll
        for (int p = 0; p < 4; ++p) {
            ra[p] = *(const bf16x8*)(pA + (size_t)p * 32 * K + kt);
            rb[p] = *(const bf16x8*)(pB + (size_t)p * 32 * K + kt);
        }
        __syncthreads();
#pragma unroll
        for (int p = 0; p < 4; ++p) {
            *(bf16x8*)(lA + p * 32 * 64 + swoff) = ra[p];
            *(bf16x8*)(lB + p * 32 * 64 + swoff) = rb[p];
        }
        __syncthreads();
#pragma unroll
        for (int kc = 0; kc < 2; ++kc) {
            bf16x8 af[4], bfr[4];
#pragma unroll
            for (int f = 0; f < 4; ++f) af[f] = *(const bf16x8*)(lA + offA[f][kc]);
#pragma unroll
            for (int f = 0; f < 4; ++f) bfr[f] = *(const bf16x8*)(lB + offB[f][kc]);
#pragma unroll
            for (int mf = 0; mf < 4; ++mf)
#pragma unroll
                for (int nf = 0; nf < 4; ++nf)
                    acc[mf][nf] = __builtin_amdgcn_mfma_f32_16x16x32_bf16(
                        af[mf], bfr[nf], acc[mf][nf], 0, 0, 0);
        }
    }

    if (OUT_BF16) {
        unsigned short* C = (unsigned short*)Cp;
#pragma unroll
        for (int mf = 0; mf < 4; ++mf)
#pragma unroll
            for (int nf = 0; nf < 4; ++nf) {
                const size_t row = bm + wm + mf * 16 + l4 * 4;
                const size_t col = bn + wn + nf * 16 + l15;
#pragma unroll
                for (int j = 0; j < 4; ++j)
                    C[(row + j) * (size_t)N + col] = f2bf(acc[mf][nf][j]);
            }
    } else {
        float* C = (float*)Cp;
#pragma unroll
        for (int nf = 0; nf < 4; ++nf) {
            const size_t col = bn + wn + nf * 16 + l15;
            const float bv = bias[col];
#pragma unroll
            for (int mf = 0; mf < 4; ++mf) {
                const size_t row = bm + wm + mf * 16 + l4 * 4;
#pragma unroll
                for (int j = 0; j < 4; ++j)
                    C[(row + j) * (size_t)N + col] = acc[mf][nf][j] + bv;
            }
        }
    }
}

// ---------------------------------------------------------------------------
// 4) V transpose: qkv v-cols -> vt[bh][d][n]
// ---------------------------------------------------------------------------
__global__ void k_tr_v(const unsigned short* __restrict__ qkv, unsigned short* __restrict__ vt) {
    __shared__ alignas(16) unsigned short tile[64][72];
    const int t = threadIdx.x;
    const int bh = blockIdx.y, b = bh >> 4, h = bh & 15;
    const int nb = blockIdx.x * 64;
#pragma unroll
    for (int p = 0; p < 2; ++p) {
        const int n = p * 32 + (t >> 3), d0 = (t & 7) * 8;
        u16x8 v = *(const u16x8*)(qkv + (size_t)(b * 2048 + nb + n) * 3072 + 2048 + h * 64 + d0);
#pragma unroll
        for (int j = 0; j < 8; ++j) tile[d0 + j][n] = v[j];
    }
    __syncthreads();
#pragma unroll
    for (int p = 0; p < 2; ++p) {
        const int d = p * 32 + (t >> 3), n0 = (t & 7) * 8;
        u16x8 v = *(const u16x8*)(&tile[d][n0]);
        *(u16x8*)(vt + (size_t)(bh * 64 + d) * 2048 + nb + n0) = v;
    }
}

// ---------------------------------------------------------------------------
// 5) Flash attention, swapped-QK, verified opcodes (16x16x32 MFMA only).
//    Round-5 deltas vs validated round-4 kernel:
//      - defer-max (THR=8, log2 domain): rescale path skipped unless row max
//        grows > 8; P bounded by 2^8, fp32 accum absorbs, O/l cancels alpha.
//      - double-buffered K/V LDS, 1 barrier/iter, loads issued at loop top.
//      - P-writes paired into ds_write_b64 (same bytes, half the instrs).
//      - max3-nested max tree.
//    PV path (LDS relayout + x32 MFMA) byte-identical to round 4.
// ---------------------------------------------------------------------------
__global__ __launch_bounds__(256)
void k_attn(const unsigned short* __restrict__ qkv, const unsigned short* __restrict__ vt,
            unsigned short* __restrict__ attn_out) {
    __shared__ alignas(16) unsigned short lK[2][64 * 64];
    __shared__ alignas(16) unsigned short lV[2][64 * 64];
    __shared__ alignas(16) unsigned short lP[4][16 * 64];
    const int t = threadIdx.x, w = t >> 6, l = t & 63;
    const int l15 = l & 15, l4 = l >> 4;
    const int bh = blockIdx.y, b = bh >> 4, h = bh & 15;
    const int qb = blockIdx.x * 64;
    const float QSCALE = 0.18033688011112042f;   // 0.125 * log2(e)

    // Q B-frags in registers for the whole KV loop
    const unsigned short* qptr =
        qkv + (size_t)(b * 2048 + qb + w * 16 + l15) * 3072 + h * 64 + l4 * 8;
    const bf16x8 aq0 = *(const bf16x8*)(qptr);
    const bf16x8 aq1 = *(const bf16x8*)(qptr + 32);

    const int srow = t >> 3, sslot = t & 7;
    const int swoff = srow * 64 + ((sslot ^ (srow & 7)) << 3);
    const unsigned short* kptr = qkv + (size_t)(b * 2048 + srow) * 3072 + 1024 + h * 64 + sslot * 8;
    const unsigned short* vptr = vt + (size_t)(bh * 64 + srow) * 2048 + sslot * 8;

    // K A-frag offsets (swapped QK: A = K rows kv = nf*16+l15)
    int offK[4][2];
#pragma unroll
    for (int nf = 0; nf < 4; ++nf) {
        const int r = nf * 16 + l15;
#pragma unroll
        for (int kc = 0; kc < 2; ++kc)
            offK[nf][kc] = r * 64 + (((kc * 4 + l4) ^ (r & 7)) << 3);
    }
    // P LDS b64 write offsets: 4 contig values (q=l15, kv = nf*16 + l4*4 ..+3)
    int offPw[4];
#pragma unroll
    for (int nf = 0; nf < 4; ++nf) {
        const int c = nf * 16 + l4 * 4;
        offPw[nf] = l15 * 64 + (((c >> 3) ^ (l15 & 7)) << 3) + (c & 7);
    }

    const f32x4 zf = {0.f, 0.f, 0.f, 0.f};
    f32x4 o[4];
#pragma unroll
    for (int df = 0; df < 4; ++df) o[df] = zf;
    float m_run = -1e30f;
    float l_run = 0.f;
    unsigned short* Pw = &lP[w][0];

    // prologue: stage tile 0 into buffer 0
    {
        bf16x8 rk[2], rv[2];
#pragma unroll
        for (int p = 0; p < 2; ++p) {
            rk[p] = *(const bf16x8*)(kptr + (size_t)(p * 32) * 3072);
            rv[p] = *(const bf16x8*)(vptr + (size_t)(p * 32) * 2048);
        }
#pragma unroll
        for (int p = 0; p < 2; ++p) {
            *(bf16x8*)(&lK[0][0] + p * 32 * 64 + swoff) = rk[p];
            *(bf16x8*)(&lV[0][0] + p * 32 * 64 + swoff) = rv[p];
        }
        __syncthreads();
    }

#pragma unroll 2
    for (int kt = 0; kt < 2048; kt += 64) {
        const int cur = (kt >> 6) & 1;
        const unsigned short* K = &lK[cur][0];
        const unsigned short* V = &lV[cur][0];

        // issue next tile's global loads early (hidden under compute)
        bf16x8 rk[2], rv[2];
        const bool more = (kt + 64) < 2048;
        if (more) {
#pragma unroll
            for (int p = 0; p < 2; ++p) {
                rk[p] = *(const bf16x8*)(kptr + (size_t)(kt + 64 + p * 32) * 3072);
                rv[p] = *(const bf16x8*)(vptr + (size_t)(p * 32) * 2048 + kt + 64);
            }
        }

        // S^T = K Q^T : lane holds S_raw[kv = nf*16 + l4*4 + j][q = l15]
        f32x4 s[4];
#pragma unroll
        for (int nf = 0; nf < 4; ++nf) {
            const bf16x8 kf0 = *(const bf16x8*)(K + offK[nf][0]);
            const bf16x8 kf1 = *(const bf16x8*)(K + offK[nf][1]);
            f32x4 a = zf;
            a = __builtin_amdgcn_mfma_f32_16x16x32_bf16(kf0, aq0, a, 0, 0, 0);
            a = __builtin_amdgcn_mfma_f32_16x16x32_bf16(kf1, aq1, a, 0, 0, 0);
            s[nf] = a;
        }

        // row max over 16 lane-local values (max3-friendly nesting) + 2 shfl
        float mx = fmaxf(fmaxf(s[0][0], s[0][1]), s[0][2]);
        mx = fmaxf(fmaxf(mx, s[0][3]), s[1][0]);
        mx = fmaxf(fmaxf(mx, s[1][1]), s[1][2]);
        mx = fmaxf(fmaxf(mx, s[1][3]), s[2][0]);
        mx = fmaxf(fmaxf(mx, s[2][1]), s[2][2]);
        mx = fmaxf(fmaxf(mx, s[2][3]), s[3][0]);
        mx = fmaxf(fmaxf(mx, s[3][1]), s[3][2]);
        mx = fmaxf(mx, s[3][3]);
        mx = fmaxf(mx, __shfl_xor(mx, 16));
        mx = fmaxf(mx, __shfl_xor(mx, 32));
        mx *= QSCALE;   // into scaled log2 domain

        // defer-max: rescale only when the row max grew by > 8 (log2 domain)
        if (!__all(mx <= m_run + 8.0f)) {
            const float mn = fmaxf(m_run, mx);
            const float alpha = exp2f(m_run - mn);
            m_run = mn;
            const float a0 = __shfl(alpha, l4 * 4 + 0);
            const float a1 = __shfl(alpha, l4 * 4 + 1);
            const float a2 = __shfl(alpha, l4 * 4 + 2);
            const float a3 = __shfl(alpha, l4 * 4 + 3);
#pragma unroll
            for (int df = 0; df < 4; ++df) {
                o[df][0] *= a0; o[df][1] *= a1; o[df][2] *= a2; o[df][3] *= a3;
            }
            l_run *= alpha;
        }

        // P = exp2(QSCALE*s_raw - m); rowsum in fp32; pack to LDS (b64 writes)
        float rs = 0.f;
#pragma unroll
        for (int nf = 0; nf < 4; ++nf) {
            const float p0 = exp2f(fmaf(s[nf][0], QSCALE, -m_run));
            const float p1 = exp2f(fmaf(s[nf][1], QSCALE, -m_run));
            const float p2 = exp2f(fmaf(s[nf][2], QSCALE, -m_run));
            const float p3 = exp2f(fmaf(s[nf][3], QSCALE, -m_run));
            rs += (p0 + p1) + (p2 + p3);
            union { unsigned int d[2]; uint64_t q; } u;
            u.d[0] = cvt_pk_bf16(p0, p1);
            u.d[1] = cvt_pk_bf16(p2, p3);
            *(uint64_t*)(Pw + offPw[nf]) = u.q;
        }
        rs += __shfl_xor(rs, 16);
        rs += __shfl_xor(rs, 32);
        l_run += rs;

        // O += P V  (round-4-identical A-frag reads + x32 MFMA)
        const bf16x8 ap0 = *(const bf16x8*)(Pw + l15 * 64 + ((l4 ^ (l15 & 7)) << 3));
        const bf16x8 ap1 = *(const bf16x8*)(Pw + l15 * 64 + (((4 + l4) ^ (l15 & 7)) << 3));
#pragma unroll
        for (int df = 0; df < 4; ++df) {
            const int r = df * 16 + l15;
            const bf16x8 bv0 = *(const bf16x8*)(V + r * 64 + ((l4 ^ (r & 7)) << 3));
            const bf16x8 bv1 = *(const bf16x8*)(V + r * 64 + (((4 + l4) ^ (r & 7)) << 3));
            o[df] = __builtin_amdgcn_mfma_f32_16x16x32_bf16(ap0, bv0, o[df], 0, 0, 0);
            o[df] = __builtin_amdgcn_mfma_f32_16x16x32_bf16(ap1, bv1, o[df], 0, 0, 0);
        }

        // write next tile into the other buffer; single barrier per iter
        if (more) {
#pragma unroll
            for (int p = 0; p < 2; ++p) {
                *(bf16x8*)(&lK[cur ^ 1][0] + p * 32 * 64 + swoff) = rk[p];
                *(bf16x8*)(&lV[cur ^ 1][0] + p * 32 * 64 + swoff) = rv[p];
            }
        }
        __syncthreads();
    }

    // epilogue: O / l  (broadcast 1/l from softmax lanes to o's q rows)
    const float linv = 1.0f / l_run;
    const float r0 = __shfl(linv, l4 * 4 + 0);
    const float r1 = __shfl(linv, l4 * 4 + 1);
    const float r2 = __shfl(linv, l4 * 4 + 2);
    const float r3 = __shfl(linv, l4 * 4 + 3);
#pragma unroll
    for (int df = 0; df < 4; ++df) {
        const int d = df * 16 + l15;
        const size_t base = (size_t)(b * 2048 + qb + w * 16 + l4 * 4);
        attn_out[(base + 0) * 1024 + h * 64 + d] = f2bf(o[df][0] * r0);
        attn_out[(base + 1) * 1024 + h * 64 + d] = f2bf(o[df][1] * r1);
        attn_out[(base + 2) * 1024 + h * 64 + d] = f2bf(o[df][2] * r2);
        attn_out[(base + 3) * 1024 + h * 64 + d] = f2bf(o[df][3] * r3);
    }
}

// ---------------------------------------------------------------------------
extern "C" void kernel_launch(void* const* d_in, const int* in_sizes, int n_in,
                              void* d_out, int out_size, void* d_ws, size_t ws_size,
                              hipStream_t stream) {
    const float* x      = (const float*)d_in[0];
    const float* w_qkv  = (const float*)d_in[1];
    const float* w_proj = (const float*)d_in[2];
    const float* b_proj = (const float*)d_in[3];
    float* out = (float*)d_out;

    char* ws = (char*)d_ws;
    unsigned short* xb     = (unsigned short*)ws; ws += (size_t)4096 * 1024 * 2;
    unsigned short* wqkvT  = (unsigned short*)ws; ws += (size_t)3072 * 1024 * 2;
    unsigned short* wprojT = (unsigned short*)ws; ws += (size_t)1024 * 1024 * 2;
    unsigned short* qkv    = (unsigned short*)ws; ws += (size_t)4096 * 3072 * 2;
    unsigned short* vt     = (unsigned short*)ws; ws += (size_t)32 * 64 * 2048 * 2;
    unsigned short* attn   = (unsigned short*)ws; ws += (size_t)4096 * 1024 * 2;

    k_cvt_x<<<dim3(4096), dim3(256), 0, stream>>>(x, xb, 4096 * 1024 / 4);
    k_cvt_tr_w<<<dim3(48, 16), dim3(256), 0, stream>>>(w_qkv, wqkvT, 1024, 3072);
    k_cvt_tr_w<<<dim3(16, 16), dim3(256), 0, stream>>>(w_proj, wprojT, 1024, 1024);
    k_gemm_bt<1><<<dim3(24, 32), dim3(256), 0, stream>>>(xb, wqkvT, (void*)qkv, (const float*)nullptr, 4096, 3072, 1024);
    k_tr_v<<<dim3(32, 32), dim3(256), 0, stream>>>(qkv, vt);
    k_attn<<<dim3(32, 32), dim3(256), 0, stream>>>(qkv, vt, attn);
    k_gemm_bt<0><<<dim3(8, 32), dim3(256), 0, stream>>>(attn, wprojT, (void*)out, b_proj, 4096, 1024, 1024);
}